// Round 15
// baseline (380.031 us; speedup 1.0000x reference)
//
#include <hip/hip_runtime.h>

typedef _Float16 f16x8 __attribute__((ext_vector_type(8)));
typedef _Float16 f16x4 __attribute__((ext_vector_type(4)));
typedef float    f32x4 __attribute__((ext_vector_type(4)));

#define GAMMA_F 0.00390625f

// ---------------------------------------------------------------------------
// prep: fp32 -> fp16 row conversion + row sum-of-squares (for x and sv)
// ---------------------------------------------------------------------------
__global__ __launch_bounds__(256) void prep_rows_kernel(
    const float* __restrict__ src, _Float16* __restrict__ dst,
    float* __restrict__ sq, int nrows)
{
    int lane = threadIdx.x & 63, w = threadIdx.x >> 6;
    int row = blockIdx.x * 4 + w;
    if (row >= nrows) return;
    float4 v = ((const float4*)(src + (size_t)row * 256))[lane];
    f16x4 h;
    h[0] = (_Float16)v.x; h[1] = (_Float16)v.y;
    h[2] = (_Float16)v.z; h[3] = (_Float16)v.w;
    *((f16x4*)(dst + (size_t)row * 256) + lane) = h;
    float ss = v.x*v.x + v.y*v.y + v.z*v.z + v.w*v.w;
#pragma unroll
    for (int off = 32; off; off >>= 1) ss += __shfl_down(ss, off);
    if (lane == 0) sq[row] = ss;
}

__global__ __launch_bounds__(256) void cvt_kernel(
    const float* __restrict__ src, _Float16* __restrict__ dst, int n4)
{
    int i = blockIdx.x * 256 + threadIdx.x;
    if (i < n4) {
        float4 v = ((const float4*)src)[i];
        f16x4 h;
        h[0] = (_Float16)v.x; h[1] = (_Float16)v.y;
        h[2] = (_Float16)v.z; h[3] = (_Float16)v.w;
        ((f16x4*)dst)[i] = h;
    }
}

// ---------------------------------------------------------------------------
// 256x256-tile GEMM, asm-staged (SADDR form), FOUR phases/iter (r12/r14
// schedule, best-measured), LDS-transpose epilogue with wide stores.
// K-loop: Phase = [RFENCE; ks0 reads; stage; (counted vmcnt)] BAR
//                 [ks1 reads; 32 MFMA].
// vmcnt ledger: P1=A->s^1, P2=B->s+vmcnt(4), P3=A->s, P4=B->s^1+vmcnt(4).
// Epilogue: K-loop LDS is dead (128KB) and C-tile is exactly 256x256 fp16
// = 128KB -> barrier; ds_write_b16 the 128 epilogue values; barrier; each
// wave re-reads its 32 rows as b128 and stores 16 coalesced dwordx4/thread
// (vs 128 scalar 2B stores: 8x fewer VMEM insts, no partial-line writes).
//   MODE 0: C = exp(-g*(e0[m] + e1[n] - 2*acc))
//   MODE 1: C = relu(acc + e0[n])
// ---------------------------------------------------------------------------
#define SBAR()   __builtin_amdgcn_s_barrier()
#define RFENCE() asm volatile("" ::: "memory")

// LDS-DMA global load, SADDR form: 32-bit per-lane voffset + SGPR base.
#define GLDS(voff, sbase, uoff)                                                \
    asm volatile("s_mov_b32 m0, %2\n\t"                                        \
                 "global_load_lds_dwordx4 %0, %1\n\t"                          \
                 "s_mov_b32 m0, -1"                                            \
                 :: "v"(voff), "s"(sbase), "s"(uoff))

#define UOF(x) __builtin_amdgcn_readfirstlane((x) + wb)

// stage the full CURRENT A/B tile (4 uniform streams each) into slot s
#define STAGE_A(s) do {                                                        \
    GLDS(voffA, aS0, UOF((s)*32768));                                          \
    GLDS(voffA, aS1, UOF((s)*32768 + 8192));                                   \
    GLDS(voffA, aS2, UOF((s)*32768 + 16384));                                  \
    GLDS(voffA, aS3, UOF((s)*32768 + 24576));                                  \
} while (0)
#define STAGE_B(s) do {                                                        \
    GLDS(voffB, bS0, UOF(65536 + (s)*32768));                                  \
    GLDS(voffB, bS1, UOF(65536 + (s)*32768 + 8192));                           \
    GLDS(voffB, bS2, UOF(65536 + (s)*32768 + 16384));                          \
    GLDS(voffB, bS3, UOF(65536 + (s)*32768 + 24576));                          \
} while (0)
#define ADV_A() do { aS0 += 64; aS1 += 64; aS2 += 64; aS3 += 64; } while (0)
#define ADV_B() do { bS0 += 64; bS1 += 64; bS2 += 64; bS3 += 64; } while (0)

#define RD_A0(s, mh) do { _Pragma("unroll") for (int mi = 0; mi < 4; ++mi)     \
    a0f[mi] = *(const f16x8*)(ldsb + aO0 + (s)*32768 + (mh)*8192 + mi*2048);   \
} while (0)
#define RD_A1(s, mh) do { _Pragma("unroll") for (int mi = 0; mi < 4; ++mi)     \
    a1f[mi] = *(const f16x8*)(ldsb + aO1 + (s)*32768 + (mh)*8192 + mi*2048);   \
} while (0)
#define RD_B0A(s, nh) do { _Pragma("unroll") for (int nb = 0; nb < 2; ++nb)    \
    bA0[nb] = *(const f16x8*)(ldsb + bO0 + (s)*32768 + (nh)*4096 + nb*2048);   \
} while (0)
#define RD_B1A(s, nh) do { _Pragma("unroll") for (int nb = 0; nb < 2; ++nb)    \
    bA1[nb] = *(const f16x8*)(ldsb + bO1 + (s)*32768 + (nh)*4096 + nb*2048);   \
} while (0)
#define RD_B0B(s, nh) do { _Pragma("unroll") for (int nb = 0; nb < 2; ++nb)    \
    bB0[nb] = *(const f16x8*)(ldsb + bO0 + (s)*32768 + (nh)*4096 + nb*2048);   \
} while (0)
#define RD_B1B(s, nh) do { _Pragma("unroll") for (int nb = 0; nb < 2; ++nb)    \
    bB1[nb] = *(const f16x8*)(ldsb + bO1 + (s)*32768 + (nh)*4096 + nb*2048);   \
} while (0)

#define MFMA8(af, bf, mh, nh) do {                                             \
    _Pragma("unroll") for (int mi = 0; mi < 4; ++mi)                           \
    _Pragma("unroll") for (int nb = 0; nb < 2; ++nb)                           \
        acc[(mh)*4+mi][(nh)*2+nb] = __builtin_amdgcn_mfma_f32_16x16x32_f16(    \
            af[mi], bf[nb], acc[(mh)*4+mi][(nh)*2+nb], 0, 0, 0);               \
} while (0)

#define MFMA32(mh) do {                                                        \
    __builtin_amdgcn_s_setprio(1);                                             \
    MFMA8(a0f, bA0, mh, 0); MFMA8(a1f, bA1, mh, 0);                            \
    MFMA8(a0f, bB0, mh, 1); MFMA8(a1f, bB1, mh, 1);                            \
    __builtin_amdgcn_s_setprio(0);                                             \
} while (0)

template <int MODE, int K>
__global__ __launch_bounds__(512, 1) void gemm256_kernel(
    const _Float16* __restrict__ A, const _Float16* __restrict__ B,
    _Float16* __restrict__ C, const float* __restrict__ e0,
    const float* __restrict__ e1)
{
    constexpr int KT = K / 64;
    constexpr int NITER = KT / 2;
    __shared__ f16x8 lds[8192];   // A bytes [0,65536): 2 slots; B: [65536,131072)
    char* ldsb = (char*)lds;

    const int t    = threadIdx.x;
    const int lane = t & 63, w = t >> 6;
    const int wb   = w << 10;                     // wave-uniform LDS base part
    const int wr   = w >> 2, wc = w & 3;          // 2 x 4 wave grid
    const int lrow = lane & 15, kq = lane >> 4;

    // keep lds formally stored-to (reads fed by asm-invisible staging)
    int poison = 0;
    asm volatile("" : "+v"(poison));
    if (poison) lds[0] = f16x8{};

    // XCD-aware bijective swizzle (grid % 8 == 0 by construction)
    int bid  = blockIdx.x;
    int cpx  = (int)(gridDim.x >> 3);
    int lbid = (bid & 7) * cpx + (bid >> 3);
    int bm   = lbid >> 2, bn = lbid & 3;          // NB = 1024/256 = 4
    int rowA0 = bm * 256, rowB0 = bn * 256;

    // LDS-read base byte offsets
    const int aO0 = ((wr*128 + lrow)*8 + ( kq      ^ (lrow & 7))) * 16;
    const int aO1 = ((wr*128 + lrow)*8 + ((4 + kq) ^ (lrow & 7))) * 16;
    const int bO0 = 65536 + ((wc*64 + lrow)*8 + ( kq      ^ (lrow & 7))) * 16;
    const int bO1 = 65536 + ((wc*64 + lrow)*8 + ((4 + kq) ^ (lrow & 7))) * 16;

    // T8 staging addressing: per-lane 32-bit voffset + uniform SGPR bases
    const int prow  = t >> 3;
    const int cg    = (t & 7) ^ (prow & 7);
    const int voffA = (prow * K + cg * 8) * 2;    // bytes
    const int voffB = voffA;
    const _Float16* aS0 = A + (size_t)rowA0 * K;  // uniform -> SGPR
    const _Float16* aS1 = aS0 + (size_t) 64 * K;
    const _Float16* aS2 = aS0 + (size_t)128 * K;
    const _Float16* aS3 = aS0 + (size_t)192 * K;
    const _Float16* bS0 = B + (size_t)rowB0 * K;
    const _Float16* bS1 = bS0 + (size_t) 64 * K;
    const _Float16* bS2 = bS0 + (size_t)128 * K;
    const _Float16* bS3 = bS0 + (size_t)192 * K;

    f32x4 acc[8][4];
#pragma unroll
    for (int i = 0; i < 8; ++i)
#pragma unroll
        for (int j = 0; j < 4; ++j) acc[i][j] = (f32x4){0.f, 0.f, 0.f, 0.f};

    f16x8 a0f[4], a1f[4], bA0[2], bA1[2], bB0[2], bB1[2];

    // ---- prologue: tile0 -> slot0, tile1 -> slot1 (16 loads/thread) ----
    STAGE_A(0); STAGE_B(0); ADV_A(); ADV_B();
    STAGE_A(1); STAGE_B(1); ADV_A(); ADV_B();               // now at tile2
    asm volatile("s_waitcnt vmcnt(8)" ::: "memory");        // tile0 landed
    SBAR();

    for (int j = 0; j < NITER; ++j) {
        const bool last = (j == NITER - 1);

        // ---- P1: slot0, row-half 0 ----
        RFENCE();
        RD_A0(0, 0); RD_B0A(0, 0); RD_B0B(0, 1);
        if (j > 0) { STAGE_A(1); ADV_A(); }         // tile 2j+1 A -> s1
        SBAR();
        RD_A1(0, 0); RD_B1A(0, 0); RD_B1B(0, 1);
        MFMA32(0);
        // ---- P2: slot0, row-half 1 ----
        RFENCE();
        RD_A0(0, 1);
        if (!last) {
            STAGE_B(0); ADV_B();                    // tile 2j+2 B -> s0
            asm volatile("s_waitcnt vmcnt(4)" ::: "memory");  // slot1 landed
        } else {
            asm volatile("s_waitcnt vmcnt(0)" ::: "memory");
        }
        SBAR();
        RD_A1(0, 1);
        MFMA32(1);
        // ---- P3: slot1, row-half 0 ----
        RFENCE();
        RD_A0(1, 0); RD_B0A(1, 0); RD_B0B(1, 1);
        if (!last) { STAGE_A(0); ADV_A(); }         // tile 2j+2 A -> s0
        SBAR();
        RD_A1(1, 0); RD_B1A(1, 0); RD_B1B(1, 1);
        MFMA32(0);
        // ---- P4: slot1, row-half 1 ----
        RFENCE();
        RD_A0(1, 1);
        if (!last) {
            STAGE_B(1); ADV_B();                    // tile 2j+3 B -> s1
            asm volatile("s_waitcnt vmcnt(4)" ::: "memory");  // slot0 landed
        }
        SBAR();
        RD_A1(1, 1);
        MFMA32(1);
    }

    // ---- epilogue: LDS-transpose C-tile + wide coalesced stores ----
    RFENCE();
    SBAR();     // all waves' K-loop LDS reads complete; LDS now dead
    {
        const int gc0 = rowB0 + wc * 64;
        float ecol[4];
#pragma unroll
        for (int ni = 0; ni < 4; ++ni)
            ecol[ni] = (MODE == 0) ? e1[gc0 + ni * 16 + lrow]
                                   : e0[gc0 + ni * 16 + lrow];
        const int rloc0 = wr * 128 + kq * 4;          // local row base
        const int cloc0 = wc * 64 + lrow;             // local col base
#pragma unroll
        for (int mi = 0; mi < 8; ++mi) {
#pragma unroll
            for (int jj = 0; jj < 4; ++jj) {
                int r = rloc0 + mi * 16 + jj;
                float xr = (MODE == 0) ? e0[rowA0 + r] : 0.f;
#pragma unroll
                for (int ni = 0; ni < 4; ++ni) {
                    float v = acc[mi][ni][jj];
                    if (MODE == 0) {
                        v = __expf(-GAMMA_F * (xr + ecol[ni] - 2.f * v));
                    } else {
                        v += ecol[ni];
                        v = fmaxf(v, 0.f);
                    }
                    *(_Float16*)(ldsb + r * 512 + (cloc0 + ni * 16) * 2) =
                        (_Float16)v;
                }
            }
        }
    }
    RFENCE();
    SBAR();     // C-tile image complete in LDS
    {
        const int l31 = lane & 31, lh = lane >> 5;
#pragma unroll
        for (int i = 0; i < 16; ++i) {
            int rloc = w * 32 + i * 2 + lh;
            f16x8 v = *(const f16x8*)(ldsb + rloc * 512 + l31 * 16);
            *(f16x8*)(C + (size_t)(rowA0 + rloc) * 1024 + rowB0 + l31 * 8) = v;
        }
    }
}

// ---------------------------------------------------------------------------
// head: out[b][o] = sum_s h2[b][s]*Wh[o][s] + bh[o], o in {0,1}
// ---------------------------------------------------------------------------
__global__ __launch_bounds__(256) void head_kernel(
    const _Float16* __restrict__ h2, const float* __restrict__ Wh,
    const float* __restrict__ bh, float* __restrict__ out)
{
    int lane = threadIdx.x & 63, w = threadIdx.x >> 6;
    int row = blockIdx.x * 4 + w;
    const _Float16* hp = h2 + (size_t)row * 1024;
    float s0 = 0.f, s1 = 0.f;
#pragma unroll
    for (int i = 0; i < 2; ++i) {
        int base = (i * 64 + lane) * 8;
        f16x8 hv = *(const f16x8*)(hp + base);
#pragma unroll
        for (int j = 0; j < 8; ++j) {
            float hj = (float)hv[j];
            s0 = fmaf(hj, Wh[base + j], s0);
            s1 = fmaf(hj, Wh[1024 + base + j], s1);
        }
    }
#pragma unroll
    for (int off = 32; off; off >>= 1) {
        s0 += __shfl_down(s0, off);
        s1 += __shfl_down(s1, off);
    }
    if (lane == 0) {
        out[(size_t)row * 2 + 0] = s0 + bh[0];
        out[(size_t)row * 2 + 1] = s1 + bh[1];
    }
}

// ---------------------------------------------------------------------------
extern "C" void kernel_launch(void* const* d_in, const int* in_sizes, int n_in,
                              void* d_out, int out_size, void* d_ws, size_t ws_size,
                              hipStream_t stream)
{
    const float* x  = (const float*)d_in[0];
    const float* sv = (const float*)d_in[1];
    const float* W1 = (const float*)d_in[2];
    const float* b1 = (const float*)d_in[3];
    const float* W2 = (const float*)d_in[4];
    const float* b2 = (const float*)d_in[5];
    const float* Wh = (const float*)d_in[6];
    const float* bh = (const float*)d_in[7];
    float* out = (float*)d_out;
    char* ws = (char*)d_ws;

    // ---- persistent region (~4.6 MB) ----
    constexpr size_t OFF_SV = 0;
    constexpr size_t OFF_W1 = OFF_SV + 524288;
    constexpr size_t OFF_W2 = OFF_W1 + 2097152;
    constexpr size_t OFF_S2 = OFF_W2 + 2097152;
    constexpr size_t PERSIST = OFF_S2 + 4096;

    _Float16* svf = (_Float16*)(ws + OFF_SV);
    _Float16* w1f = (_Float16*)(ws + OFF_W1);
    _Float16* w2f = (_Float16*)(ws + OFF_W2);
    float*    s2v = (float*)(ws + OFF_S2);

    // ---- adaptive batch chunking ----
    int Bc = 65536;
    while (Bc > 256 && PERSIST + (size_t)Bc * 4100ULL > ws_size) Bc >>= 1;

    char* chunk_base = ws + PERSIST;
    _Float16* kb  = (_Float16*)chunk_base;                        // Bc x 1024 fp16
    _Float16* h1b = (_Float16*)(chunk_base + (size_t)Bc * 2048);  // Bc x 1024 fp16
    _Float16* xf  = h1b;                                          // overlapped (dies before h1 written)
    float*    x2v = (float*)(chunk_base + (size_t)Bc * 4096);

    prep_rows_kernel<<<1024 / 4, 256, 0, stream>>>(sv, svf, s2v, 1024);
    cvt_kernel<<<1024, 256, 0, stream>>>(W1, w1f, 262144);
    cvt_kernel<<<1024, 256, 0, stream>>>(W2, w2f, 262144);

    int nchunks = 65536 / Bc;
    int ggrid   = (Bc / 256) * 4;
    for (int c = 0; c < nchunks; ++c) {
        const float* xc = x + (size_t)c * Bc * 256;
        prep_rows_kernel<<<Bc / 4, 256, 0, stream>>>(xc, xf, x2v, Bc);
        gemm256_kernel<0, 256><<<ggrid, 512, 0, stream>>>(xf, svf, kb, x2v, s2v);
        gemm256_kernel<1, 1024><<<ggrid, 512, 0, stream>>>(kb, w1f, h1b, b1, nullptr);
        gemm256_kernel<1, 1024><<<ggrid, 512, 0, stream>>>(h1b, w2f, kb, b2, nullptr);
        head_kernel<<<Bc / 4, 256, 0, stream>>>(kb, Wh, bh, out + (size_t)c * Bc * 2);
    }
}

// Round 16
// 368.386 us; speedup vs baseline: 1.0316x; 1.0316x over previous
//
#include <hip/hip_runtime.h>

typedef _Float16 f16x8 __attribute__((ext_vector_type(8)));
typedef _Float16 f16x4 __attribute__((ext_vector_type(4)));
typedef float    f32x4 __attribute__((ext_vector_type(4)));

#define GAMMA_F 0.00390625f

// ---------------------------------------------------------------------------
// prep: fp32 -> fp16 row conversion + row sum-of-squares (for x and sv)
// ---------------------------------------------------------------------------
__global__ __launch_bounds__(256) void prep_rows_kernel(
    const float* __restrict__ src, _Float16* __restrict__ dst,
    float* __restrict__ sq, int nrows)
{
    int lane = threadIdx.x & 63, w = threadIdx.x >> 6;
    int row = blockIdx.x * 4 + w;
    if (row >= nrows) return;
    float4 v = ((const float4*)(src + (size_t)row * 256))[lane];
    f16x4 h;
    h[0] = (_Float16)v.x; h[1] = (_Float16)v.y;
    h[2] = (_Float16)v.z; h[3] = (_Float16)v.w;
    *((f16x4*)(dst + (size_t)row * 256) + lane) = h;
    float ss = v.x*v.x + v.y*v.y + v.z*v.z + v.w*v.w;
#pragma unroll
    for (int off = 32; off; off >>= 1) ss += __shfl_down(ss, off);
    if (lane == 0) sq[row] = ss;
}

__global__ __launch_bounds__(256) void cvt_kernel(
    const float* __restrict__ src, _Float16* __restrict__ dst, int n4)
{
    int i = blockIdx.x * 256 + threadIdx.x;
    if (i < n4) {
        float4 v = ((const float4*)src)[i];
        f16x4 h;
        h[0] = (_Float16)v.x; h[1] = (_Float16)v.y;
        h[2] = (_Float16)v.z; h[3] = (_Float16)v.w;
        ((f16x4*)dst)[i] = h;
    }
}

// ---------------------------------------------------------------------------
// 256x256-tile GEMM, asm-staged (SADDR form), FOUR phases/iter — r14 config
// (best measured: 368.6us total, 66us/GEMM, MfmaUtil 43%).
// Structure is ~85% of its LDS-BW-bound ceiling: per K-tile/CU this geometry
// moves 192KB LDS reads + 64KB staged writes vs ~112-128B/cyc LDS budget,
// co-saturated with the 2480cyc MFMA-pipe time -> MfmaUtil ceiling ~50-55%.
// r15's LDS-transpose epilogue regressed (8-way ds_write conflicts + extra
// barriers); direct stores restored.
// Phase = [RFENCE; ks0 reads; stage; (counted vmcnt)] BAR [ks1 reads; 32 MFMA].
// vmcnt ledger: P1=A->s^1, P2=B->s+vmcnt(4), P3=A->s, P4=B->s^1+vmcnt(4).
//   MODE 0: C = exp(-g*(e0[m] + e1[n] - 2*acc))
//   MODE 1: C = relu(acc + e0[n])
// ---------------------------------------------------------------------------
#define SBAR()   __builtin_amdgcn_s_barrier()
#define RFENCE() asm volatile("" ::: "memory")

// LDS-DMA global load, SADDR form: 32-bit per-lane voffset + SGPR base.
#define GLDS(voff, sbase, uoff)                                                \
    asm volatile("s_mov_b32 m0, %2\n\t"                                        \
                 "global_load_lds_dwordx4 %0, %1\n\t"                          \
                 "s_mov_b32 m0, -1"                                            \
                 :: "v"(voff), "s"(sbase), "s"(uoff))

#define UOF(x) __builtin_amdgcn_readfirstlane((x) + wb)

// stage the full CURRENT A/B tile (4 uniform streams each) into slot s
#define STAGE_A(s) do {                                                        \
    GLDS(voffA, aS0, UOF((s)*32768));                                          \
    GLDS(voffA, aS1, UOF((s)*32768 + 8192));                                   \
    GLDS(voffA, aS2, UOF((s)*32768 + 16384));                                  \
    GLDS(voffA, aS3, UOF((s)*32768 + 24576));                                  \
} while (0)
#define STAGE_B(s) do {                                                        \
    GLDS(voffB, bS0, UOF(65536 + (s)*32768));                                  \
    GLDS(voffB, bS1, UOF(65536 + (s)*32768 + 8192));                           \
    GLDS(voffB, bS2, UOF(65536 + (s)*32768 + 16384));                          \
    GLDS(voffB, bS3, UOF(65536 + (s)*32768 + 24576));                          \
} while (0)
#define ADV_A() do { aS0 += 64; aS1 += 64; aS2 += 64; aS3 += 64; } while (0)
#define ADV_B() do { bS0 += 64; bS1 += 64; bS2 += 64; bS3 += 64; } while (0)

#define RD_A0(s, mh) do { _Pragma("unroll") for (int mi = 0; mi < 4; ++mi)     \
    a0f[mi] = *(const f16x8*)(ldsb + aO0 + (s)*32768 + (mh)*8192 + mi*2048);   \
} while (0)
#define RD_A1(s, mh) do { _Pragma("unroll") for (int mi = 0; mi < 4; ++mi)     \
    a1f[mi] = *(const f16x8*)(ldsb + aO1 + (s)*32768 + (mh)*8192 + mi*2048);   \
} while (0)
#define RD_B0A(s, nh) do { _Pragma("unroll") for (int nb = 0; nb < 2; ++nb)    \
    bA0[nb] = *(const f16x8*)(ldsb + bO0 + (s)*32768 + (nh)*4096 + nb*2048);   \
} while (0)
#define RD_B1A(s, nh) do { _Pragma("unroll") for (int nb = 0; nb < 2; ++nb)    \
    bA1[nb] = *(const f16x8*)(ldsb + bO1 + (s)*32768 + (nh)*4096 + nb*2048);   \
} while (0)
#define RD_B0B(s, nh) do { _Pragma("unroll") for (int nb = 0; nb < 2; ++nb)    \
    bB0[nb] = *(const f16x8*)(ldsb + bO0 + (s)*32768 + (nh)*4096 + nb*2048);   \
} while (0)
#define RD_B1B(s, nh) do { _Pragma("unroll") for (int nb = 0; nb < 2; ++nb)    \
    bB1[nb] = *(const f16x8*)(ldsb + bO1 + (s)*32768 + (nh)*4096 + nb*2048);   \
} while (0)

#define MFMA8(af, bf, mh, nh) do {                                             \
    _Pragma("unroll") for (int mi = 0; mi < 4; ++mi)                           \
    _Pragma("unroll") for (int nb = 0; nb < 2; ++nb)                           \
        acc[(mh)*4+mi][(nh)*2+nb] = __builtin_amdgcn_mfma_f32_16x16x32_f16(    \
            af[mi], bf[nb], acc[(mh)*4+mi][(nh)*2+nb], 0, 0, 0);               \
} while (0)

#define MFMA32(mh) do {                                                        \
    __builtin_amdgcn_s_setprio(1);                                             \
    MFMA8(a0f, bA0, mh, 0); MFMA8(a1f, bA1, mh, 0);                            \
    MFMA8(a0f, bB0, mh, 1); MFMA8(a1f, bB1, mh, 1);                            \
    __builtin_amdgcn_s_setprio(0);                                             \
} while (0)

template <int MODE, int K>
__global__ __launch_bounds__(512, 1) void gemm256_kernel(
    const _Float16* __restrict__ A, const _Float16* __restrict__ B,
    _Float16* __restrict__ C, const float* __restrict__ e0,
    const float* __restrict__ e1)
{
    constexpr int KT = K / 64;
    constexpr int NITER = KT / 2;
    __shared__ f16x8 lds[8192];   // A bytes [0,65536): 2 slots; B: [65536,131072)
    char* ldsb = (char*)lds;

    const int t    = threadIdx.x;
    const int lane = t & 63, w = t >> 6;
    const int wb   = w << 10;                     // wave-uniform LDS base part
    const int wr   = w >> 2, wc = w & 3;          // 2 x 4 wave grid
    const int lrow = lane & 15, kq = lane >> 4;

    // keep lds formally stored-to (reads fed by asm-invisible staging)
    int poison = 0;
    asm volatile("" : "+v"(poison));
    if (poison) lds[0] = f16x8{};

    // XCD-aware bijective swizzle (grid % 8 == 0 by construction)
    int bid  = blockIdx.x;
    int cpx  = (int)(gridDim.x >> 3);
    int lbid = (bid & 7) * cpx + (bid >> 3);
    int bm   = lbid >> 2, bn = lbid & 3;          // NB = 1024/256 = 4
    int rowA0 = bm * 256, rowB0 = bn * 256;

    // LDS-read base byte offsets
    const int aO0 = ((wr*128 + lrow)*8 + ( kq      ^ (lrow & 7))) * 16;
    const int aO1 = ((wr*128 + lrow)*8 + ((4 + kq) ^ (lrow & 7))) * 16;
    const int bO0 = 65536 + ((wc*64 + lrow)*8 + ( kq      ^ (lrow & 7))) * 16;
    const int bO1 = 65536 + ((wc*64 + lrow)*8 + ((4 + kq) ^ (lrow & 7))) * 16;

    // T8 staging addressing: per-lane 32-bit voffset + uniform SGPR bases
    const int prow  = t >> 3;
    const int cg    = (t & 7) ^ (prow & 7);
    const int voffA = (prow * K + cg * 8) * 2;    // bytes
    const int voffB = voffA;
    const _Float16* aS0 = A + (size_t)rowA0 * K;  // uniform -> SGPR
    const _Float16* aS1 = aS0 + (size_t) 64 * K;
    const _Float16* aS2 = aS0 + (size_t)128 * K;
    const _Float16* aS3 = aS0 + (size_t)192 * K;
    const _Float16* bS0 = B + (size_t)rowB0 * K;
    const _Float16* bS1 = bS0 + (size_t) 64 * K;
    const _Float16* bS2 = bS0 + (size_t)128 * K;
    const _Float16* bS3 = bS0 + (size_t)192 * K;

    f32x4 acc[8][4];
#pragma unroll
    for (int i = 0; i < 8; ++i)
#pragma unroll
        for (int j = 0; j < 4; ++j) acc[i][j] = (f32x4){0.f, 0.f, 0.f, 0.f};

    f16x8 a0f[4], a1f[4], bA0[2], bA1[2], bB0[2], bB1[2];

    // ---- prologue: tile0 -> slot0, tile1 -> slot1 (16 loads/thread) ----
    STAGE_A(0); STAGE_B(0); ADV_A(); ADV_B();
    STAGE_A(1); STAGE_B(1); ADV_A(); ADV_B();               // now at tile2
    asm volatile("s_waitcnt vmcnt(8)" ::: "memory");        // tile0 landed
    SBAR();

    for (int j = 0; j < NITER; ++j) {
        const bool last = (j == NITER - 1);

        // ---- P1: slot0, row-half 0 ----
        RFENCE();
        RD_A0(0, 0); RD_B0A(0, 0); RD_B0B(0, 1);
        if (j > 0) { STAGE_A(1); ADV_A(); }         // tile 2j+1 A -> s1
        SBAR();
        RD_A1(0, 0); RD_B1A(0, 0); RD_B1B(0, 1);
        MFMA32(0);
        // ---- P2: slot0, row-half 1 ----
        RFENCE();
        RD_A0(0, 1);
        if (!last) {
            STAGE_B(0); ADV_B();                    // tile 2j+2 B -> s0
            asm volatile("s_waitcnt vmcnt(4)" ::: "memory");  // slot1 landed
        } else {
            asm volatile("s_waitcnt vmcnt(0)" ::: "memory");
        }
        SBAR();
        RD_A1(0, 1);
        MFMA32(1);
        // ---- P3: slot1, row-half 0 ----
        RFENCE();
        RD_A0(1, 0); RD_B0A(1, 0); RD_B0B(1, 1);
        if (!last) { STAGE_A(0); ADV_A(); }         // tile 2j+2 A -> s0
        SBAR();
        RD_A1(1, 0); RD_B1A(1, 0); RD_B1B(1, 1);
        MFMA32(0);
        // ---- P4: slot1, row-half 1 ----
        RFENCE();
        RD_A0(1, 1);
        if (!last) {
            STAGE_B(1); ADV_B();                    // tile 2j+3 B -> s1
            asm volatile("s_waitcnt vmcnt(4)" ::: "memory");  // slot0 landed
        }
        SBAR();
        RD_A1(1, 1);
        MFMA32(1);
    }

    // ---- epilogue (direct stores — r15's LDS-transpose variant regressed) ----
    int gr0 = rowA0 + wr * 128;
    int gc0 = rowB0 + wc * 64;
    float ecol[4];
#pragma unroll
    for (int ni = 0; ni < 4; ++ni)
        ecol[ni] = (MODE == 0) ? e1[gc0 + ni * 16 + lrow]
                               : e0[gc0 + ni * 16 + lrow];
#pragma unroll
    for (int mi = 0; mi < 8; ++mi) {
#pragma unroll
        for (int jj = 0; jj < 4; ++jj) {
            int row = gr0 + mi * 16 + kq * 4 + jj;
            float xr = (MODE == 0) ? e0[row] : 0.f;
            size_t base = (size_t)row * 1024 + gc0 + lrow;
#pragma unroll
            for (int ni = 0; ni < 4; ++ni) {
                float v = acc[mi][ni][jj];
                if (MODE == 0) {
                    v = __expf(-GAMMA_F * (xr + ecol[ni] - 2.f * v));
                } else {
                    v += ecol[ni];
                    v = fmaxf(v, 0.f);
                }
                C[base + (size_t)ni * 16] = (_Float16)v;
            }
        }
    }
}

// ---------------------------------------------------------------------------
// head: out[b][o] = sum_s h2[b][s]*Wh[o][s] + bh[o], o in {0,1}
// ---------------------------------------------------------------------------
__global__ __launch_bounds__(256) void head_kernel(
    const _Float16* __restrict__ h2, const float* __restrict__ Wh,
    const float* __restrict__ bh, float* __restrict__ out)
{
    int lane = threadIdx.x & 63, w = threadIdx.x >> 6;
    int row = blockIdx.x * 4 + w;
    const _Float16* hp = h2 + (size_t)row * 1024;
    float s0 = 0.f, s1 = 0.f;
#pragma unroll
    for (int i = 0; i < 2; ++i) {
        int base = (i * 64 + lane) * 8;
        f16x8 hv = *(const f16x8*)(hp + base);
#pragma unroll
        for (int j = 0; j < 8; ++j) {
            float hj = (float)hv[j];
            s0 = fmaf(hj, Wh[base + j], s0);
            s1 = fmaf(hj, Wh[1024 + base + j], s1);
        }
    }
#pragma unroll
    for (int off = 32; off; off >>= 1) {
        s0 += __shfl_down(s0, off);
        s1 += __shfl_down(s1, off);
    }
    if (lane == 0) {
        out[(size_t)row * 2 + 0] = s0 + bh[0];
        out[(size_t)row * 2 + 1] = s1 + bh[1];
    }
}

// ---------------------------------------------------------------------------
extern "C" void kernel_launch(void* const* d_in, const int* in_sizes, int n_in,
                              void* d_out, int out_size, void* d_ws, size_t ws_size,
                              hipStream_t stream)
{
    const float* x  = (const float*)d_in[0];
    const float* sv = (const float*)d_in[1];
    const float* W1 = (const float*)d_in[2];
    const float* b1 = (const float*)d_in[3];
    const float* W2 = (const float*)d_in[4];
    const float* b2 = (const float*)d_in[5];
    const float* Wh = (const float*)d_in[6];
    const float* bh = (const float*)d_in[7];
    float* out = (float*)d_out;
    char* ws = (char*)d_ws;

    // ---- persistent region (~4.6 MB) ----
    constexpr size_t OFF_SV = 0;
    constexpr size_t OFF_W1 = OFF_SV + 524288;
    constexpr size_t OFF_W2 = OFF_W1 + 2097152;
    constexpr size_t OFF_S2 = OFF_W2 + 2097152;
    constexpr size_t PERSIST = OFF_S2 + 4096;

    _Float16* svf = (_Float16*)(ws + OFF_SV);
    _Float16* w1f = (_Float16*)(ws + OFF_W1);
    _Float16* w2f = (_Float16*)(ws + OFF_W2);
    float*    s2v = (float*)(ws + OFF_S2);

    // ---- adaptive batch chunking ----
    int Bc = 65536;
    while (Bc > 256 && PERSIST + (size_t)Bc * 4100ULL > ws_size) Bc >>= 1;

    char* chunk_base = ws + PERSIST;
    _Float16* kb  = (_Float16*)chunk_base;                        // Bc x 1024 fp16
    _Float16* h1b = (_Float16*)(chunk_base + (size_t)Bc * 2048);  // Bc x 1024 fp16
    _Float16* xf  = h1b;                                          // overlapped (dies before h1 written)
    float*    x2v = (float*)(chunk_base + (size_t)Bc * 4096);

    prep_rows_kernel<<<1024 / 4, 256, 0, stream>>>(sv, svf, s2v, 1024);
    cvt_kernel<<<1024, 256, 0, stream>>>(W1, w1f, 262144);
    cvt_kernel<<<1024, 256, 0, stream>>>(W2, w2f, 262144);

    int nchunks = 65536 / Bc;
    int ggrid   = (Bc / 256) * 4;
    for (int c = 0; c < nchunks; ++c) {
        const float* xc = x + (size_t)c * Bc * 256;
        prep_rows_kernel<<<Bc / 4, 256, 0, stream>>>(xc, xf, x2v, Bc);
        gemm256_kernel<0, 256><<<ggrid, 512, 0, stream>>>(xf, svf, kb, x2v, s2v);
        gemm256_kernel<1, 1024><<<ggrid, 512, 0, stream>>>(kb, w1f, h1b, b1, nullptr);
        gemm256_kernel<1, 1024><<<ggrid, 512, 0, stream>>>(h1b, w2f, kb, b2, nullptr);
        head_kernel<<<Bc / 4, 256, 0, stream>>>(kb, Wh, bh, out + (size_t)c * Bc * 2);
    }
}